// Round 5
// baseline (277.836 us; speedup 1.0000x reference)
//
#include <hip/hip_runtime.h>
#include <hip/hip_bf16.h>
#include <math.h>

#define C_CH 8
#define H_DIM 512
#define BS 32768            // B*S
#define K_DIM 4096          // C*H
#define EPS 1e-5f

#define TM 32
#define TK 32
#define NKT (K_DIM / TK)    // 128 K-tiles
#define GRP 4               // k-tiles per barrier group
#define NGRP (NKT / GRP)    // 32 groups
#define AELEMS (TM * TK * GRP)   // 4096 bf16 per group buffer (8 KB)

typedef __bf16 bf16x8 __attribute__((ext_vector_type(8)));
typedef float  floatx4 __attribute__((ext_vector_type(4)));

// tanh-form GELU, exp2-folded: gelu(v) ~= v * sigmoid(1.5957691*(v+0.044715 v^3))
// constants pre-multiplied by log2(e); max abs dev from exact erf-gelu ~3e-4.
__device__ __forceinline__ float gelu_fast(float v) {
    float x2 = v * fmaf(v * v, 0.102943215f, 2.30220815f);   // x*log2e
    float e = __builtin_amdgcn_exp2f(-x2);
    return v * __builtin_amdgcn_rcpf(1.0f + e);
}

// Prep kernel, grid = 1024 + 8 blocks x 256 threads.
// Blocks [0,1024): mod_w fp32 [512][4096] -> bf16 workspace in MFMA B-fragment
//   chunk layout: chunk(kt 0..127, ntile 0..31) of 64 lanes x 16B; lane l holds
//   B[col = ntile*16 + (l&15)][k = kt*32 + (l>>4)*8 + i], i=0..7.
// Blocks [1024,1032): per-channel encoder-LN fold (c = blockIdx-1024):
//   Wf[c][j] = gamma*(w - mean(w)), Bf[c][j] = gamma*(b - mean(b)),
//   st[c] = {var_w, 2*cov_wb, var_b}.
__global__ __launch_bounds__(256) void prep_kernel(
    const float* __restrict__ w, __bf16* __restrict__ o,
    const float* __restrict__ enc_w, const float* __restrict__ enc_b,
    const float* __restrict__ enc_gamma,
    float* __restrict__ Wf, float* __restrict__ Bf, float* __restrict__ st)
{
    __shared__ float red[4][5];
    if (blockIdx.x < 1024) {
        int gtid  = blockIdx.x * 256 + threadIdx.x;   // 0..262143
        int lane  = gtid & 63;
        int chunk = gtid >> 6;                        // 0..4095
        int kt    = chunk >> 5;
        int ntile = chunk & 31;
        int col   = ntile * 16 + (lane & 15);
        int k     = kt * 32 + (lane >> 4) * 8;
        const float* src = w + (size_t)col * K_DIM + k;
        float4 a = *(const float4*)src;
        float4 b = *(const float4*)(src + 4);
        bf16x8 h;
        h[0] = (__bf16)a.x; h[1] = (__bf16)a.y; h[2] = (__bf16)a.z; h[3] = (__bf16)a.w;
        h[4] = (__bf16)b.x; h[5] = (__bf16)b.y; h[6] = (__bf16)b.z; h[7] = (__bf16)b.w;
        *(bf16x8*)(o + (size_t)gtid * 8) = h;
    } else {
        const int c = blockIdx.x - 1024;              // 0..7
        const int t = threadIdx.x;                    // 0..255
        const float* wp = enc_w + c * H_DIM;
        const float* bp = enc_b + c * H_DIM;
        const float* gp = enc_gamma + c * H_DIM;
        float w0 = wp[t], w1 = wp[t + 256];
        float b0 = bp[t], b1 = bp[t + 256];
        float sw  = w0 + w1;
        float sb  = b0 + b1;
        float sww = fmaf(w0, w0, w1 * w1);
        float sbb = fmaf(b0, b0, b1 * b1);
        float swb = fmaf(w0, b0, w1 * b1);
        #pragma unroll
        for (int off = 32; off; off >>= 1) {
            sw  += __shfl_xor(sw,  off);
            sb  += __shfl_xor(sb,  off);
            sww += __shfl_xor(sww, off);
            sbb += __shfl_xor(sbb, off);
            swb += __shfl_xor(swb, off);
        }
        int wv = t >> 6, ln = t & 63;
        if (ln == 0) {
            red[wv][0] = sw;  red[wv][1] = sb;  red[wv][2] = sww;
            red[wv][3] = sbb; red[wv][4] = swb;
        }
        __syncthreads();
        float tsw  = red[0][0] + red[1][0] + red[2][0] + red[3][0];
        float tsb  = red[0][1] + red[1][1] + red[2][1] + red[3][1];
        float tsww = red[0][2] + red[1][2] + red[2][2] + red[3][2];
        float tsbb = red[0][3] + red[1][3] + red[2][3] + red[3][3];
        float tswb = red[0][4] + red[1][4] + red[2][4] + red[3][4];
        const float inv = 1.0f / (float)H_DIM;
        float mw = tsw * inv, mb = tsb * inv;
        if (t == 0) {
            st[c * 4 + 0] = tsww * inv - mw * mw;           // var_w
            st[c * 4 + 1] = 2.0f * (tswb * inv - mw * mb);  // 2*cov
            st[c * 4 + 2] = tsbb * inv - mb * mb;           // var_b
        }
        float g0 = gp[t], g1 = gp[t + 256];
        Wf[c * H_DIM + t]       = g0 * (w0 - mw);
        Wf[c * H_DIM + t + 256] = g1 * (w1 - mw);
        Bf[c * H_DIM + t]       = g0 * (b0 - mb);
        Bf[c * H_DIM + t + 256] = g1 * (b1 - mb);
    }
}

// Fused: analytic enc-LN -> gelu -> GEMM(mod_w^T) -> +mod_b -> LayerNorm -> gelu.
// 512 threads / 8 waves, wave-tile 32x64 (acc 32 AGPR -> 32 VGPR freed for a
// ring-4 half-set B prefetch, ~1.5 sub-iterations of latency cover). A staged
// ONCE per 4-k-tile group (one param-load stall per group, VALU burst covers
// B loads crossing the barrier). Raw barriers: lgkmcnt-only drain, so B loads
// stay in flight across group boundaries (no vmcnt(0) flush).
template <int USE_WS>
__global__ __launch_bounds__(512, 4) void fused_gemm_kernel(
    const float* __restrict__ x,
    const float* __restrict__ enc_w,
    const float* __restrict__ enc_b,
    const float* __restrict__ enc_gamma,
    const float* __restrict__ enc_beta,
    const float* __restrict__ mod_w,      // fp32 fallback
    const __bf16* __restrict__ Wb,        // bf16 frag-layout (workspace)
    const float* __restrict__ Wf,         // folded gamma*(w-mw)   (workspace)
    const float* __restrict__ Bf,         // folded gamma*(b-mb)   (workspace)
    const float* __restrict__ st,         // per-channel {vw,2cwb,vb} (workspace)
    const float* __restrict__ mod_b,
    const float* __restrict__ mod_gamma,
    const float* __restrict__ mod_beta,
    float* __restrict__ out)
{
    __shared__ float stats[C_CH][5];            // legacy path only
    __shared__ float pS[C_CH][TM];
    __shared__ float qS[C_CH][TM];
    __shared__ float rS[C_CH][TM];              // legacy path only
    __shared__ __align__(16) __bf16 Als[2][AELEMS];   // 16 KB
    __shared__ float redS[TM][8];
    __shared__ float redQ[TM][8];
    __shared__ float muS[TM];
    __shared__ float invS[TM];

    const int tid  = threadIdx.x;
    const int wave = tid >> 6;        // 0..7
    const int lane = tid & 63;
    const int lr   = lane & 15;
    const int lq   = lane >> 4;
    const int row0 = blockIdx.x * TM;

    // ---- B-frag loader: one half (j=0: nt 0,1; j=1: nt 2,3) of one k-tile ----
    const __bf16* baseB = Wb + ((size_t)(wave * 4) * 64 + lane) * 8;
    auto loadB = [&](int kt, int j, bf16x8 (&dst)[2]) {
        if (USE_WS) {
            const __bf16* bp = baseB + ((size_t)kt * 32 + j * 2) * 512;
            dst[0] = *(const bf16x8*)bp;
            dst[1] = *(const bf16x8*)(bp + 512);
        } else {
            const int kk = kt * 32 + lq * 8;
            #pragma unroll
            for (int n2 = 0; n2 < 2; ++n2) {
                int col = wave * 64 + (j * 2 + n2) * 16 + lr;
                const float* src = mod_w + (size_t)col * K_DIM + kk;
                float4 a = *(const float4*)src;
                float4 b = *(const float4*)(src + 4);
                bf16x8 h;
                h[0] = (__bf16)a.x; h[1] = (__bf16)a.y; h[2] = (__bf16)a.z; h[3] = (__bf16)a.w;
                h[4] = (__bf16)b.x; h[5] = (__bf16)b.y; h[6] = (__bf16)b.z; h[7] = (__bf16)b.w;
                dst[n2] = h;
            }
        }
    };

    // ring-4 half-sets: even kt -> rA(j0), rB(j1); odd kt -> rC(j0), rD(j1)
    bf16x8 rA[2], rB[2], rC[2], rD[2];
    loadB(0, 0, rA);              // issue 8 B loads before anything else
    loadB(0, 1, rB);
    loadB(1, 0, rC);
    loadB(1, 1, rD);

    if (USE_WS) {
        // ---- per-(channel,row) p,q from precomputed channel stats ----
        if (tid < C_CH * TM) {
            int c = tid >> 5, m = tid & 31;
            float xv = x[c * BS + row0 + m];
            float vw = st[c * 4 + 0], cwb2 = st[c * 4 + 1], vb = st[c * 4 + 2];
            float q = rsqrtf(fmaf(xv, fmaf(xv, vw, cwb2), vb) + EPS);
            pS[c][m] = xv * q;
            qS[c][m] = q;
        }
    } else {
        // ---- legacy: in-kernel stats, then p,q,r ----
        {
            const int c = wave;
            float sw = 0.f, sb = 0.f, sww = 0.f, sbb = 0.f, swb = 0.f;
            for (int jj = lane; jj < H_DIM; jj += 64) {
                float w = enc_w[c * H_DIM + jj];
                float b = enc_b[c * H_DIM + jj];
                sw += w; sb += b;
                sww = fmaf(w, w, sww);
                sbb = fmaf(b, b, sbb);
                swb = fmaf(w, b, swb);
            }
            #pragma unroll
            for (int off = 32; off; off >>= 1) {
                sw  += __shfl_xor(sw,  off);
                sb  += __shfl_xor(sb,  off);
                sww += __shfl_xor(sww, off);
                sbb += __shfl_xor(sbb, off);
                swb += __shfl_xor(swb, off);
            }
            if (lane == 0) {
                const float inv = 1.0f / (float)H_DIM;
                float mw = sw * inv, mb = sb * inv;
                stats[c][0] = mw;
                stats[c][1] = mb;
                stats[c][2] = sww * inv - mw * mw;
                stats[c][3] = sbb * inv - mb * mb;
                stats[c][4] = swb * inv - mw * mb;
            }
        }
        __syncthreads();
        if (tid < C_CH * TM) {
            int c = tid >> 5, m = tid & 31;
            float xv = x[c * BS + row0 + m];
            float mw = stats[c][0], mb = stats[c][1];
            float vw = stats[c][2], vb = stats[c][3], cwb = stats[c][4];
            float var = fmaf(xv, fmaf(xv, vw, 2.0f * cwb), vb);
            float q = rsqrtf(var + EPS);
            float p = xv * q;
            pS[c][m] = p;
            qS[c][m] = q;
            rS[c][m] = -fmaf(p, mw, q * mb);
        }
    }
    __syncthreads();

    // ---- A staging decomposition: one 16B chunk-slot per thread per group ----
    // group tile = 4 kt x 32 rows x 32 k; thread t: sub=t>>7, mt=(t>>6)&1,
    // lane sl holds A[row=mt*16+(sl&15)][k = sub*32 + (sl>>4)*8 + i], i=0..7.
    const int ssub  = tid >> 7;
    const int smt   = (tid >> 6) & 1;
    const int sl    = tid & 63;
    const int srow  = smt * 16 + (sl & 15);
    const int skk   = ssub * TK + (sl >> 4) * 8;
    const int sdoff = (ssub * 2 + smt) * 512 + sl * 8;

    auto stageGroup = [&](int g1, __bf16* dstbuf) {
        const int c = g1 >> 2;
        const float p = pS[c][srow], q = qS[c][srow];
        const int k0 = g1 * 128 + skk;
        float4 w0 = *(const float4*)(Wf + k0);
        float4 w1 = *(const float4*)(Wf + k0 + 4);
        float4 b0 = *(const float4*)(Bf + k0);
        float4 b1 = *(const float4*)(Bf + k0 + 4);
        float4 e0 = *(const float4*)(enc_beta + k0);
        float4 e1 = *(const float4*)(enc_beta + k0 + 4);
        float fw[8] = {w0.x, w0.y, w0.z, w0.w, w1.x, w1.y, w1.z, w1.w};
        float fb[8] = {b0.x, b0.y, b0.z, b0.w, b1.x, b1.y, b1.z, b1.w};
        float fe[8] = {e0.x, e0.y, e0.z, e0.w, e1.x, e1.y, e1.z, e1.w};
        bf16x8 hv;
        #pragma unroll
        for (int i = 0; i < 8; ++i) {
            float v = fmaf(p, fw[i], fmaf(q, fb[i], fe[i]));
            hv[i] = (__bf16)gelu_fast(v);
        }
        *(bf16x8*)(dstbuf + sdoff) = hv;
    };

    auto stageGroupL = [&](int g1, __bf16* dstbuf) {
        const int c = g1 >> 2;
        const float p = pS[c][srow], q = qS[c][srow], r = rS[c][srow];
        const int k0 = g1 * 128 + skk;
        float4 w0 = *(const float4*)(enc_w + k0);
        float4 w1 = *(const float4*)(enc_w + k0 + 4);
        float4 b0 = *(const float4*)(enc_b + k0);
        float4 b1 = *(const float4*)(enc_b + k0 + 4);
        float4 g0 = *(const float4*)(enc_gamma + k0);
        float4 g1v = *(const float4*)(enc_gamma + k0 + 4);
        float4 e0 = *(const float4*)(enc_beta + k0);
        float4 e1 = *(const float4*)(enc_beta + k0 + 4);
        float fw[8] = {w0.x, w0.y, w0.z, w0.w, w1.x, w1.y, w1.z, w1.w};
        float fb[8] = {b0.x, b0.y, b0.z, b0.w, b1.x, b1.y, b1.z, b1.w};
        float fg[8] = {g0.x, g0.y, g0.z, g0.w, g1v.x, g1v.y, g1v.z, g1v.w};
        float fe[8] = {e0.x, e0.y, e0.z, e0.w, e1.x, e1.y, e1.z, e1.w};
        bf16x8 hv;
        #pragma unroll
        for (int i = 0; i < 8; ++i) {
            float t = fmaf(p, fw[i], fmaf(q, fb[i], r));
            float v = fmaf(t, fg[i], fe[i]);
            hv[i] = (__bf16)gelu_fast(v);
        }
        *(bf16x8*)(dstbuf + sdoff) = hv;
    };

    floatx4 acc[2][4];
    #pragma unroll
    for (int i = 0; i < 2; ++i)
        #pragma unroll
        for (int j = 0; j < 4; ++j)
            acc[i][j] = (floatx4){0.f, 0.f, 0.f, 0.f};

    // one sub-iteration: 2 A-frag reads, 2 MFMA clusters of 4 with half-set
    // reload right after each cluster's consume (distance to next use ~1.5 subs)
    auto mfmaSub = [&](const __bf16* Acur, int sub, int kt,
                       bf16x8 (&sE)[2], bf16x8 (&sO)[2]) {
        bf16x8 af0 = *(const bf16x8*)(Acur + (sub * 2 + 0) * 512 + lane * 8);
        bf16x8 af1 = *(const bf16x8*)(Acur + (sub * 2 + 1) * 512 + lane * 8);
        __builtin_amdgcn_s_setprio(1);
        acc[0][0] = __builtin_amdgcn_mfma_f32_16x16x32_bf16(af0, sE[0], acc[0][0], 0, 0, 0);
        acc[1][0] = __builtin_amdgcn_mfma_f32_16x16x32_bf16(af1, sE[0], acc[1][0], 0, 0, 0);
        acc[0][1] = __builtin_amdgcn_mfma_f32_16x16x32_bf16(af0, sE[1], acc[0][1], 0, 0, 0);
        acc[1][1] = __builtin_amdgcn_mfma_f32_16x16x32_bf16(af1, sE[1], acc[1][1], 0, 0, 0);
        __builtin_amdgcn_s_setprio(0);
        if (kt + 2 < NKT) loadB(kt + 2, 0, sE);
        __builtin_amdgcn_s_setprio(1);
        acc[0][2] = __builtin_amdgcn_mfma_f32_16x16x32_bf16(af0, sO[0], acc[0][2], 0, 0, 0);
        acc[1][2] = __builtin_amdgcn_mfma_f32_16x16x32_bf16(af1, sO[0], acc[1][2], 0, 0, 0);
        acc[0][3] = __builtin_amdgcn_mfma_f32_16x16x32_bf16(af0, sO[1], acc[0][3], 0, 0, 0);
        acc[1][3] = __builtin_amdgcn_mfma_f32_16x16x32_bf16(af1, sO[1], acc[1][3], 0, 0, 0);
        __builtin_amdgcn_s_setprio(0);
        if (kt + 2 < NKT) loadB(kt + 2, 1, sO);
    };

    // stage group 0, make visible
    if (USE_WS) stageGroup(0, &Als[0][0]);
    else        stageGroupL(0, &Als[0][0]);
    asm volatile("s_waitcnt lgkmcnt(0)" ::: "memory");
    __builtin_amdgcn_s_barrier();
    __builtin_amdgcn_sched_barrier(0);

    for (int g = 0; g < NGRP; ++g) {
        const __bf16* cur = &Als[g & 1][0];
        __bf16*       nxt = &Als[(g + 1) & 1][0];
        const int kt0 = g * GRP;

        // stage the NEXT group's A in one burst (param loads -> VALU burst;
        // covers the B half-sets reloaded late in the previous group)
        if (g + 1 < NGRP) {
            if (USE_WS) stageGroup(g + 1, nxt);
            else        stageGroupL(g + 1, nxt);
        }

        mfmaSub(cur, 0, kt0 + 0, rA, rB);
        mfmaSub(cur, 1, kt0 + 1, rC, rD);
        mfmaSub(cur, 2, kt0 + 2, rA, rB);
        mfmaSub(cur, 3, kt0 + 3, rC, rD);

        // group boundary: drain LDS ops only; B global loads stay in flight
        asm volatile("s_waitcnt lgkmcnt(0)" ::: "memory");
        __builtin_amdgcn_s_barrier();
        __builtin_amdgcn_sched_barrier(0);
    }

    // ---- fused epilogue: +mod_b, LayerNorm over 512 cols, gelu, store ----
    float mbv[4], gv[4], bev[4];
    #pragma unroll
    for (int nt = 0; nt < 4; ++nt) {
        int col = wave * 64 + nt * 16 + lr;
        mbv[nt] = mod_b[col];
        gv[nt]  = mod_gamma[col];
        bev[nt] = mod_beta[col];
    }
    #pragma unroll
    for (int mt = 0; mt < 2; ++mt)
        #pragma unroll
        for (int nt = 0; nt < 4; ++nt)
            #pragma unroll
            for (int r = 0; r < 4; ++r)
                acc[mt][nt][r] += mbv[nt];

    // per-row partial sums within this wave's 64 cols
    #pragma unroll
    for (int mt = 0; mt < 2; ++mt) {
        #pragma unroll
        for (int r = 0; r < 4; ++r) {
            float s = 0.f, ss = 0.f;
            #pragma unroll
            for (int nt = 0; nt < 4; ++nt) {
                float y = acc[mt][nt][r];
                s += y;
                ss = fmaf(y, y, ss);
            }
            #pragma unroll
            for (int off = 1; off < 16; off <<= 1) {
                s  += __shfl_xor(s,  off);
                ss += __shfl_xor(ss, off);
            }
            if (lr == 0) {
                int row = mt * 16 + lq * 4 + r;
                redS[row][wave] = s;
                redQ[row][wave] = ss;
            }
        }
    }
    __syncthreads();
    if (tid < TM) {
        float s = 0.f, ss = 0.f;
        #pragma unroll
        for (int w = 0; w < 8; ++w) {
            s  += redS[tid][w];
            ss += redQ[tid][w];
        }
        const float inv_n = 1.0f / (float)H_DIM;
        float mu  = s * inv_n;
        float var = ss * inv_n - mu * mu;
        muS[tid]  = mu;
        invS[tid] = rsqrtf(var + EPS);
    }
    __syncthreads();

    #pragma unroll
    for (int mt = 0; mt < 2; ++mt) {
        #pragma unroll
        for (int r = 0; r < 4; ++r) {
            int row = mt * 16 + lq * 4 + r;
            float mu  = muS[row];
            float inv = invS[row];
            float* op = out + (size_t)(row0 + row) * H_DIM;
            #pragma unroll
            for (int nt = 0; nt < 4; ++nt) {
                int col = wave * 64 + nt * 16 + lr;
                float t = fmaf((acc[mt][nt][r] - mu) * inv, gv[nt], bev[nt]);
                op[col] = gelu_fast(t);
            }
        }
    }
}

extern "C" void kernel_launch(void* const* d_in, const int* in_sizes, int n_in,
                              void* d_out, int out_size, void* d_ws, size_t ws_size,
                              hipStream_t stream) {
    const float* x         = (const float*)d_in[0];
    const float* enc_w     = (const float*)d_in[1];
    const float* enc_b     = (const float*)d_in[2];
    const float* enc_gamma = (const float*)d_in[3];
    const float* enc_beta  = (const float*)d_in[4];
    const float* mod_w     = (const float*)d_in[5];
    const float* mod_b     = (const float*)d_in[6];
    const float* mod_gamma = (const float*)d_in[7];
    const float* mod_beta  = (const float*)d_in[8];
    float* out = (float*)d_out;

    const size_t wb_bytes = (size_t)H_DIM * K_DIM * sizeof(__bf16);   // 4 MB
    const size_t wf_off   = wb_bytes;
    const size_t bf_off   = wf_off + (size_t)C_CH * H_DIM * sizeof(float);  // +16 KB
    const size_t st_off   = bf_off + (size_t)C_CH * H_DIM * sizeof(float);  // +16 KB
    const size_t need     = st_off + (size_t)C_CH * 4 * sizeof(float);

    int use_ws = (ws_size >= need) ? 1 : 0;
    __bf16* Wb = (__bf16*)d_ws;
    float*  Wf = (float*)((char*)d_ws + wf_off);
    float*  Bf = (float*)((char*)d_ws + bf_off);
    float*  st = (float*)((char*)d_ws + st_off);

    if (use_ws) {
        prep_kernel<<<1024 + C_CH, 256, 0, stream>>>(
            mod_w, Wb, enc_w, enc_b, enc_gamma, Wf, Bf, st);
        fused_gemm_kernel<1><<<BS / TM, 512, 0, stream>>>(
            x, enc_w, enc_b, enc_gamma, enc_beta, mod_w, Wb, Wf, Bf, st,
            mod_b, mod_gamma, mod_beta, out);
    } else {
        fused_gemm_kernel<0><<<BS / TM, 512, 0, stream>>>(
            x, enc_w, enc_b, enc_gamma, enc_beta, mod_w, Wb,
            (const float*)0, (const float*)0, (const float*)0,
            mod_b, mod_gamma, mod_beta, out);
    }
}